// Round 17
// baseline (134.412 us; speedup 1.0000x reference)
//
#include <hip/hip_runtime.h>
#include <math.h>

#define S 1024
#define DIMM 1024
#define G 4
#define HPG 4
#define HD 64
#define PW 32
#define SCALE 0.125f
#define LNEPS 1e-5f

typedef __bf16 bf16x8 __attribute__((ext_vector_type(8)));
typedef float  f32x4  __attribute__((ext_vector_type(4)));
typedef float  f32x16 __attribute__((ext_vector_type(16)));

// ------- fused f32->bf16 conversions + bias concat + RoPE cos/sin table ------
__global__ __launch_bounds__(256)
void cvt_all(const float* __restrict__ x, const float* __restrict__ kv,
             const float* __restrict__ qw, const float* __restrict__ kw,
             const float* __restrict__ vw, const float* __restrict__ ow,
             const float* __restrict__ kb, const float* __restrict__ vb_,
             __bf16* __restrict__ xh, __bf16* __restrict__ kvh,
             __bf16* __restrict__ qwh, __bf16* __restrict__ kvwh,
             __bf16* __restrict__ owh, __bf16* __restrict__ owl,
             float* __restrict__ kvbias, float2* __restrict__ rope) {
    if (blockIdx.x >= 5377) {
        const int idx = (blockIdx.x - 5377) * 256 + threadIdx.x;   // [0,16384)
        const int t = idx >> 4, i = idx & 15;
        const float theta = expf(-0.57564627324851f * (float)i);
        const float ang = (float)t * theta;
        rope[idx] = make_float2(cosf(ang), sinf(ang));
        return;
    }
    if (blockIdx.x == 5376) {
        kvbias[threadIdx.x]       = kb[threadIdx.x];
        kvbias[256 + threadIdx.x] = vb_[threadIdx.x];
        return;
    }
    long j = (long)blockIdx.x * 256 + threadIdx.x;
    const float* src; __bf16* dh; __bf16* dl = nullptr;
    if (j < 524288)            { src = x;  dh = xh; }
    else if ((j -= 524288) < 524288) { src = kv; dh = kvh; }
    else if ((j -= 524288) < 131072) { src = qw; dh = qwh; }
    else if ((j -= 131072) < 32768)  { src = kw; dh = kvwh; }
    else if ((j -= 32768) < 32768)   { src = vw; dh = kvwh + 262144; }
    else { j -= 32768; src = ow; dh = owh; dl = owl; }
    const float4 a = *(const float4*)(src + j * 8);
    const float4 b = *(const float4*)(src + j * 8 + 4);
    const float v[8] = {a.x, a.y, a.z, a.w, b.x, b.y, b.z, b.w};
    bf16x8 H;
    #pragma unroll
    for (int e = 0; e < 8; ++e) H[e] = (__bf16)v[e];
    *(bf16x8*)(dh + j * 8) = H;
    if (dl != nullptr) {
        bf16x8 L;
        #pragma unroll
        for (int e = 0; e < 8; ++e) L[e] = (__bf16)(v[e] - (float)H[e]);
        *(bf16x8*)(dl + j * 8) = L;
    }
}

// ---------------- bf16 MFMA GEMM helpers ----------------
__device__ __forceinline__ void gld_lds16(const __bf16* g, __bf16* lds) {
    __builtin_amdgcn_global_load_lds(
        (const __attribute__((address_space(1))) void*)g,
        (__attribute__((address_space(3))) void*)lds, 16, 0, 0);
}

// ---------------- fused q+kv projections (NB=64, 768 blocks) ----------------
__global__ __launch_bounds__(256)
void gemm_qkv(const __bf16* __restrict__ xh,  const __bf16* __restrict__ qwh,
              const float* __restrict__ qb,   __bf16* __restrict__ q_lin,
              const __bf16* __restrict__ kvh, const __bf16* __restrict__ kvwh,
              const float* __restrict__ kvb,  __bf16* __restrict__ kv_lin) {
    constexpr int K = 1024;
    __shared__ __bf16 Ahs[128][32];
    __shared__ __bf16 Whs[64][32];

    int bid = blockIdx.x;
    const __bf16 *A, *Wm; const float* bias; __bf16* C; int N, m0, n0;
    if (bid < 512) { A = xh;  Wm = qwh;  bias = qb;  C = q_lin;  N = 1024;
                     m0 = (bid >> 4) * 128; n0 = (bid & 15) * 64; }
    else { bid -= 512; A = kvh; Wm = kvwh; bias = kvb; C = kv_lin; N = 512;
           m0 = (bid >> 3) * 128; n0 = (bid & 7) * 64; }

    const int tid = threadIdx.x;
    const int w = tid >> 6, l = tid & 63;
    const int lr = l & 15, lh = l >> 4;
    const int wr = w >> 1, wc = w & 1;
    const int srow = l >> 2, scol = (l & 3) * 8;

    f32x4 acc[4][2];
    #pragma unroll
    for (int i = 0; i < 4; ++i)
        #pragma unroll
        for (int j = 0; j < 2; ++j) acc[i][j] = (f32x4){0.f, 0.f, 0.f, 0.f};

    const __bf16* Abp = A  + (size_t)(m0 + srow) * K + scol;
    const __bf16* Wbp = Wm + (size_t)(n0 + srow) * K + scol;

    for (int k0 = 0; k0 < K; k0 += 32) {
        #pragma unroll
        for (int c = 0; c < 2; ++c)
            gld_lds16(Abp + (size_t)(c * 4 + w) * 16 * K + k0, &Ahs[(c * 4 + w) * 16][0]);
        gld_lds16(Wbp + (size_t)w * 16 * K + k0, &Whs[w * 16][0]);
        __syncthreads();

        bf16x8 af[4], bfr[2];
        #pragma unroll
        for (int i = 0; i < 4; ++i) af[i] = *(const bf16x8*)&Ahs[wr * 64 + 16 * i + lr][lh * 8];
        #pragma unroll
        for (int j = 0; j < 2; ++j) bfr[j] = *(const bf16x8*)&Whs[wc * 32 + 16 * j + lr][lh * 8];
        #pragma unroll
        for (int i = 0; i < 4; ++i)
            #pragma unroll
            for (int j = 0; j < 2; ++j)
                acc[i][j] = __builtin_amdgcn_mfma_f32_16x16x32_bf16(af[i], bfr[j], acc[i][j], 0, 0, 0);
        __syncthreads();
    }

    float bv[2];
    #pragma unroll
    for (int j = 0; j < 2; ++j) bv[j] = bias[n0 + wc * 32 + 16 * j + lr];
    #pragma unroll
    for (int i = 0; i < 4; ++i) {
        const int mb = m0 + wr * 64 + 16 * i + 4 * lh;
        #pragma unroll
        for (int j = 0; j < 2; ++j) {
            const int n = n0 + wc * 32 + 16 * j + lr;
            #pragma unroll
            for (int r = 0; r < 4; ++r)
                C[(size_t)(mb + r) * N + n] = (__bf16)(acc[i][j][r] + bv[j]);
        }
    }
}

// ---------------- o-projection: 2-term W-split, N=64 tiles -------------------
__global__ __launch_bounds__(256)
void gemm_o(const __bf16* __restrict__ Ah, const __bf16* __restrict__ Wh,
            const __bf16* __restrict__ Wl, const float* __restrict__ bias,
            float* __restrict__ Cout) {
    constexpr int K = 1024, N = 1024;
    __shared__ __bf16 Ahs[128][32];
    __shared__ __bf16 Whs[64][32];
    __shared__ __bf16 Wls[64][32];

    const int tid = threadIdx.x;
    const int w = tid >> 6, l = tid & 63;
    const int lr = l & 15, lh = l >> 4;
    const int wr = w >> 1, wc = w & 1;
    const int m0 = blockIdx.y * 128, n0 = blockIdx.x * 64;
    const int srow = l >> 2, scol = (l & 3) * 8;

    f32x4 acc[4][2];
    #pragma unroll
    for (int i = 0; i < 4; ++i)
        #pragma unroll
        for (int j = 0; j < 2; ++j) acc[i][j] = (f32x4){0.f, 0.f, 0.f, 0.f};

    const __bf16* Abp = Ah + (size_t)(m0 + srow) * K + scol;
    const __bf16* Whp = Wh + (size_t)(n0 + srow) * K + scol;
    const __bf16* Wlp = Wl + (size_t)(n0 + srow) * K + scol;

    for (int k0 = 0; k0 < K; k0 += 32) {
        #pragma unroll
        for (int c = 0; c < 2; ++c)
            gld_lds16(Abp + (size_t)(c * 4 + w) * 16 * K + k0, &Ahs[(c * 4 + w) * 16][0]);
        gld_lds16(Whp + (size_t)w * 16 * K + k0, &Whs[w * 16][0]);
        gld_lds16(Wlp + (size_t)w * 16 * K + k0, &Wls[w * 16][0]);
        __syncthreads();

        bf16x8 af[4], bh[2], bl[2];
        #pragma unroll
        for (int i = 0; i < 4; ++i) af[i] = *(const bf16x8*)&Ahs[wr * 64 + 16 * i + lr][lh * 8];
        #pragma unroll
        for (int j = 0; j < 2; ++j) {
            bh[j] = *(const bf16x8*)&Whs[wc * 32 + 16 * j + lr][lh * 8];
            bl[j] = *(const bf16x8*)&Wls[wc * 32 + 16 * j + lr][lh * 8];
        }
        #pragma unroll
        for (int i = 0; i < 4; ++i)
            #pragma unroll
            for (int j = 0; j < 2; ++j) {
                acc[i][j] = __builtin_amdgcn_mfma_f32_16x16x32_bf16(af[i], bh[j], acc[i][j], 0, 0, 0);
                acc[i][j] = __builtin_amdgcn_mfma_f32_16x16x32_bf16(af[i], bl[j], acc[i][j], 0, 0, 0);
            }
        __syncthreads();
    }

    float bv[2];
    #pragma unroll
    for (int j = 0; j < 2; ++j) bv[j] = bias[n0 + wc * 32 + 16 * j + lr];
    #pragma unroll
    for (int i = 0; i < 4; ++i) {
        const int mb = m0 + wr * 64 + 16 * i + 4 * lh;
        #pragma unroll
        for (int j = 0; j < 2; ++j) {
            const int n = n0 + wc * 32 + 16 * j + lr;
            #pragma unroll
            for (int r = 0; r < 4; ++r)
                Cout[(size_t)(mb + r) * N + n] = acc[i][j][r] + bv[j];
        }
    }
}

// ---------------- wave helpers ----------------
__device__ inline float wave64_sum(float v) {
    #pragma unroll
    for (int off = 32; off >= 1; off >>= 1) v += __shfl_xor(v, off);
    return v;
}

// ---------------- fused transforms (RoPE via table; Q pre-scaled by SC2) -----
__global__ __launch_bounds__(256)
void transforms_all(const __bf16* __restrict__ q_lin, const __bf16* __restrict__ kv_lin,
                    const float* __restrict__ qn_g, const float* __restrict__ qn_b,
                    const float* __restrict__ kn_g, const float* __restrict__ kn_b,
                    const int* __restrict__ qtime, const int* __restrict__ ktime,
                    const int* __restrict__ qvar, const int* __restrict__ kvar,
                    const float* __restrict__ var_emb, const float2* __restrict__ rope,
                    __bf16* __restrict__ q_nb, __bf16* __restrict__ kfrag,
                    __bf16* __restrict__ vfrag) {
    __shared__ float T[64][65];
    const int bid = blockIdx.x;
    const int lane = threadIdx.x & 63;
    constexpr float SC2 = 0.125f * 1.4426950408889634f;   // 0.18033688

    if (bid < 16384) {
        const int row = bid * 4 + (threadIdx.x >> 6);
        const int s   = row & (S - 1);
        const int bgh = row >> 10;
        const int b   = bgh >> 4;
        const int gh  = bgh & 15;
        float x = (float)q_lin[(size_t)(b * S + s) * DIMM + gh * HD + lane];
        const float m = wave64_sum(x) * (1.0f / 64.0f);
        const float d = x - m;
        const float v = wave64_sum(d * d) * (1.0f / 64.0f);
        float y = d * rsqrtf(v + LNEPS) * qn_g[lane] + qn_b[lane];
        const float partner = __shfl_xor(y, 1);
        if (lane < PW) {
            const float2 cs = rope[qtime[b * S + s] * 16 + (lane >> 1)];
            y = cs.x * y + cs.y * ((lane & 1) ? partner : -partner);
        }
        __bf16* qrow = q_nb + (size_t)row * 80;
        qrow[lane] = (__bf16)(y * SC2);
        if (lane < 16) {
            const int qv = qvar[b * S + s];
            float ex = 0.0f;
            if (lane < 8) {
                const float dw = var_emb[16 + gh] - var_emb[gh];
                ex = (qv == lane) ? 8.0f * dw * SC2 : 0.0f;
            } else if (lane == 8) {
                ex = (8.0f * var_emb[gh] - 69.31471805599453f) * SC2;
            }
            qrow[64 + lane] = (__bf16)ex;
        }
    } else if (bid < 20480) {
        const int row = (bid - 16384) * 4 + (threadIdx.x >> 6);
        const int s   = row & (S - 1);
        const int bg  = row >> 10;
        const int b   = bg >> 2;
        const int g   = bg & 3;
        float x = (float)kv_lin[(size_t)(b * S + s) * 512 + g * HD + lane];
        const float m = wave64_sum(x) * (1.0f / 64.0f);
        const float d = x - m;
        const float v = wave64_sum(d * d) * (1.0f / 64.0f);
        float y = d * rsqrtf(v + LNEPS) * kn_g[lane] + kn_b[lane];
        const float partner = __shfl_xor(y, 1);
        if (lane < PW) {
            const float2 cs = rope[ktime[b * S + s] * 16 + (lane >> 1)];
            y = cs.x * y + cs.y * ((lane & 1) ? partner : -partner);
        }
        const int kt = s >> 6, ks = (s >> 5) & 1, lq = s & 31;
        const size_t tb = (size_t)((bg * 16 + kt) * 10 + ks * 5);
        kfrag[(tb + (lane >> 4)) * 512 + ((lane >> 3) & 1) * 256 + lq * 8 + (lane & 7)]
            = (__bf16)y;
        if (lane < 16) {
            const int kvv = kvar[b * S + s];
            const int hh = lane >> 3, e = lane & 7;
            float ex;
            if (hh == 0) ex = (kvv == e) ? 1.0f : 0.0f;
            else         ex = (e == 0) ? 1.0f : 0.0f;
            kfrag[(tb + 4) * 512 + hh * 256 + lq * 8 + e] = (__bf16)ex;
        }
    } else {
        const int vb = bid - 20480;
        const int bg = vb >> 4;
        const int kt = vb & 15;
        const int b = bg >> 2, g = bg & 3;
        const int tx = threadIdx.x & 63, ty = threadIdx.x >> 6;
        const __bf16* src = kv_lin + ((size_t)(b * S) + kt * 64) * 512 + 256 + g * HD;
        #pragma unroll
        for (int i = 0; i < 16; ++i) {
            const int kl = ty + 4 * i;
            T[kl][tx] = (float)src[(size_t)kl * 512 + tx];
        }
        __syncthreads();
        __bf16* dst = vfrag + (size_t)bg * 65536 + (size_t)kt * 4096;
        #pragma unroll
        for (int half = 0; half < 2; ++half) {
            const int c  = half * 256 + threadIdx.x;
            const int lq = c & 31;
            const int h  = (c >> 5) & 1;
            const int kc = (c >> 6) & 1;
            const int ks = (c >> 7) & 1;
            const int t  = (c >> 8) & 1;
            const int kl = 32 * ks + 16 * kc + 8 * h;
            const int d  = 32 * t + lq;
            bf16x8 o;
            #pragma unroll
            for (int e = 0; e < 8; ++e) o[e] = (__bf16)T[kl + e][d];
            *(bf16x8*)(dst + ((size_t)((t * 2 + ks) * 2 + kc) * 2 + h) * 256 + lq * 8) = o;
        }
    }
}

// ------- flash attention: 64 q-rows/wave (2 sub-tiles), bias-in-MFMA ---------
// Same 18 K/V loads per tile now feed 2x the MFMA/exp work (arith intensity 2x).
// Tripwires: VGPR_Count <= ~250, WRITE ~8MB (no spill); else revert to 32q.
__global__ __launch_bounds__(256, 2)
void flash_mfma(const __bf16* __restrict__ q_n, const __bf16* __restrict__ kfrag,
                const __bf16* __restrict__ vfrag, __bf16* __restrict__ attn_h) {
    __shared__ f32x4 Osh[2][2][8][64];
    __shared__ float lsh[2][2][64];

    // XCD-aware swizzle: 512 blocks, 8 XCDs, 64 contiguous per XCD
    const int orig = blockIdx.x;
    const int bid  = (orig & 7) * 64 + (orig >> 3);

    const int tid = threadIdx.x;
    const int w = tid >> 6, l = tid & 63;
    const int lq = l & 31;
    const int h  = l >> 5;
    const int qhalf = w >> 1, khalf = w & 1;
    const int qb  = bid & 7;
    const int bgh = bid >> 3;
    const int b = bgh >> 4, gh = bgh & 15;
    const int bg = bgh >> 2;
    const int q0 = qb * 128 + qhalf * 64;     // wave owns q0..q0+63
    const int ktbeg = khalf * 8;

    // Q B-frags for both 32-row sub-tiles (80-dim rows, pre-scaled)
    bf16x8 qf[2][5];
    #pragma unroll
    for (int sq = 0; sq < 2; ++sq) {
        const __bf16* qbase = q_n + ((size_t)bgh * S + q0 + 32 * sq + lq) * 80 + 8 * h;
        #pragma unroll
        for (int dc = 0; dc < 4; ++dc) qf[sq][dc] = *(const bf16x8*)(qbase + 16 * dc);
        qf[sq][4] = *(const bf16x8*)(qbase + 64);
    }

    const __bf16* kptr = kfrag + (size_t)bg * 81920 + (size_t)l * 8
                       + (size_t)ktbeg * 5120;
    const __bf16* vptr = vfrag + (size_t)bg * 65536 + (size_t)l * 8
                       + (size_t)ktbeg * 4096;

    f32x16 OT[2][2];                          // [sq][t]
    #pragma unroll
    for (int sq = 0; sq < 2; ++sq)
        #pragma unroll
        for (int t = 0; t < 2; ++t)
            #pragma unroll
            for (int r = 0; r < 16; ++r) OT[sq][t][r] = 0.0f;
    float lrun[2] = {0.0f, 0.0f};

    // preload K tile ktbeg (10 chunks)
    bf16x8 kf[2][5];
    #pragma unroll
    for (int ks = 0; ks < 2; ++ks)
        #pragma unroll
        for (int dc = 0; dc < 5; ++dc)
            kf[ks][dc] = *(const bf16x8*)(kptr + (size_t)(ks * 5 + dc) * 512);
    kptr += 5120;

    for (int ti = 0; ti < 8; ++ti) {
        // V A-frags for current tile (8 x 1KB), shared by both sq
        bf16x8 vf[2][2][2];
        #pragma unroll
        for (int t = 0; t < 2; ++t)
            #pragma unroll
            for (int ks = 0; ks < 2; ++ks)
                #pragma unroll
                for (int kc = 0; kc < 2; ++kc)
                    vf[t][ks][kc] = *(const bf16x8*)
                        (vptr + (size_t)((t * 2 + ks) * 2 + kc) * 512);
        vptr += 4096;

        // QK^T + softmax per (sq, ks); st liveness bounded to one f32x16
        uint4 F[2][2][2];                     // [sq][ks][kc]
        #pragma unroll
        for (int sq = 0; sq < 2; ++sq) {
            #pragma unroll
            for (int ks = 0; ks < 2; ++ks) {
                f32x16 st;
                __builtin_amdgcn_s_setprio(1);
                {
                    f32x16 acc;
                    #pragma unroll
                    for (int r = 0; r < 16; ++r) acc[r] = 0.0f;
                    #pragma unroll
                    for (int dc = 0; dc < 5; ++dc)
                        acc = __builtin_amdgcn_mfma_f32_32x32x16_bf16(
                            kf[ks][dc], qf[sq][dc], acc, 0, 0, 0);
                    st = acc;
                }
                __builtin_amdgcn_s_setprio(0);
                unsigned int u[8];
                #pragma unroll
                for (int jj = 0; jj < 8; ++jj) {
                    const float p0 = exp2f(st[2 * jj]);
                    const float p1 = exp2f(st[2 * jj + 1]);
                    lrun[sq] += p0 + p1;
                    asm("v_cvt_pk_bf16_f32 %0, %1, %2" : "=v"(u[jj]) : "v"(p0), "v"(p1));
                }
                unsigned a0 = u[0], b0 = u[2];
                unsigned a1 = u[1], b1 = u[3];
                asm("v_permlane32_swap_b32 %0, %1" : "+v"(a0), "+v"(b0));
                asm("v_permlane32_swap_b32 %0, %1" : "+v"(a1), "+v"(b1));
                F[sq][ks][0] = make_uint4(a0, a1, b0, b1);
                unsigned a2 = u[4], b2 = u[6];
                unsigned a3 = u[5], b3 = u[7];
                asm("v_permlane32_swap_b32 %0, %1" : "+v"(a2), "+v"(b2));
                asm("v_permlane32_swap_b32 %0, %1" : "+v"(a3), "+v"(b3));
                F[sq][ks][1] = make_uint4(a2, a3, b2, b3);
            }
        }

        // prefetch next K tile (after QK consumed current kf)
        if (ti < 7) {
            #pragma unroll
            for (int ks = 0; ks < 2; ++ks)
                #pragma unroll
                for (int dc = 0; dc < 5; ++dc)
                    kf[ks][dc] = *(const bf16x8*)(kptr + (size_t)(ks * 5 + dc) * 512);
            kptr += 5120;
        }

        // PV: both sq share each vf fragment
        __builtin_amdgcn_s_setprio(1);
        #pragma unroll
        for (int t = 0; t < 2; ++t)
            #pragma unroll
            for (int sq = 0; sq < 2; ++sq)
                #pragma unroll
                for (int ks = 0; ks < 2; ++ks)
                    #pragma unroll
                    for (int kc = 0; kc < 2; ++kc)
                        OT[sq][t] = __builtin_amdgcn_mfma_f32_32x32x16_bf16(
                            vf[t][ks][kc], __builtin_bit_cast(bf16x8, F[sq][ks][kc]),
                            OT[sq][t], 0, 0, 0);
        __builtin_amdgcn_s_setprio(0);
    }

    // ---- merge the two K-halves: pure sums (static softmax reference) ----
    if (khalf) {
        #pragma unroll
        for (int sq = 0; sq < 2; ++sq) {
            #pragma unroll
            for (int t = 0; t < 2; ++t)
                #pragma unroll
                for (int c = 0; c < 4; ++c)
                    Osh[qhalf][sq][t * 4 + c][l] =
                        (f32x4){OT[sq][t][4 * c], OT[sq][t][4 * c + 1],
                                OT[sq][t][4 * c + 2], OT[sq][t][4 * c + 3]};
            lsh[qhalf][sq][l] = lrun[sq];
        }
    }
    __syncthreads();
    if (khalf) return;

    #pragma unroll
    for (int sq = 0; sq < 2; ++sq) {
        #pragma unroll
        for (int t = 0; t < 2; ++t)
            #pragma unroll
            for (int c = 0; c < 4; ++c) {
                const f32x4 o = Osh[qhalf][sq][t * 4 + c][l];
                OT[sq][t][4 * c]     += o[0];
                OT[sq][t][4 * c + 1] += o[1];
                OT[sq][t][4 * c + 2] += o[2];
                OT[sq][t][4 * c + 3] += o[3];
            }
        float lr = lrun[sq] + lsh[qhalf][sq][l];
        lr += __shfl_xor(lr, 32);
        const float linv = 1.0f / lr;

        __bf16* oh = attn_h + (size_t)(b * S + q0 + 32 * sq + lq) * DIMM + gh * HD;
        #pragma unroll
        for (int t = 0; t < 2; ++t)
            #pragma unroll
            for (int j = 0; j < 4; ++j) {
                const int d0 = 32 * t + 8 * j + 4 * h;
                unsigned short hv[4];
                #pragma unroll
                for (int c = 0; c < 4; ++c)
                    hv[c] = __builtin_bit_cast(unsigned short,
                                               (__bf16)(OT[sq][t][4 * j + c] * linv));
                *(ushort4*)(oh + d0) = make_ushort4(hv[0], hv[1], hv[2], hv[3]);
            }
    }
}

extern "C" void kernel_launch(void* const* d_in, const int* in_sizes, int n_in,
                              void* d_out, int out_size, void* d_ws, size_t ws_size,
                              hipStream_t stream) {
    const float* x     = (const float*)d_in[0];
    const float* kv    = (const float*)d_in[1];
    const float* q_w   = (const float*)d_in[2];
    const float* q_b   = (const float*)d_in[3];
    const float* k_w   = (const float*)d_in[4];
    const float* k_b   = (const float*)d_in[5];
    const float* v_w   = (const float*)d_in[6];
    const float* v_b   = (const float*)d_in[7];
    const float* o_w   = (const float*)d_in[8];
    const float* o_b   = (const float*)d_in[9];
    const float* qn_g  = (const float*)d_in[10];
    const float* qn_b  = (const float*)d_in[11];
    const float* kn_g  = (const float*)d_in[12];
    const float* kn_b  = (const float*)d_in[13];
    const float* vemb  = (const float*)d_in[14];
    const int*   qvar  = (const int*)d_in[15];
    const int*   kvar  = (const int*)d_in[16];
    const int*   qtime = (const int*)d_in[17];
    const int*   ktime = (const int*)d_in[18];
    float* out = (float*)d_out;
    char*  W   = (char*)d_ws;

    const size_t MB = 1u << 20;
    __bf16* xh     = (__bf16*)(W);                   // 0-8   -> attn_h
    __bf16* kvh    = (__bf16*)(W + 8 * MB);          // 8-16  -> q_nb
    __bf16* q_nb   = (__bf16*)(W + 8 * MB);          // 8-18  (80-dim rows)
    __bf16* q_lin  = (__bf16*)(W + 18 * MB);         // 18-26
    __bf16* kv_lin = (__bf16*)(W + 26 * MB);         // 26-30
    __bf16* qwh    = (__bf16*)(W + 30 * MB);         // 30-32
    __bf16* kvwh   = (__bf16*)(W + 32 * MB);         // 32-33
    __bf16* kfrag  = (__bf16*)(W + 33 * MB);         // 33-35.5
    __bf16* vfrag  = (__bf16*)(W + 35 * MB + MB / 2);// 35.5-37.5
    __bf16* owh    = (__bf16*)(W + 37 * MB + MB / 2);// 37.5-39.5
    __bf16* owl    = (__bf16*)(W + 39 * MB + MB / 2);// 39.5-41.5
    float*  kvb    = (float*)(W + 42 * MB);          // 2 KB
    float2* rope   = (float2*)(W + 42 * MB + 4096);  // 128 KB
    __bf16* attn_h = xh;

    dim3 blk(256);

    cvt_all<<<5441, blk, 0, stream>>>(x, kv, q_w, k_w, v_w, o_w, k_b, v_b,
                                      xh, kvh, qwh, kvwh, owh, owl, kvb, rope);

    gemm_qkv<<<768, blk, 0, stream>>>(xh, qwh, q_b, q_lin, kvh, kvwh, kvb, kv_lin);

    transforms_all<<<20736, blk, 0, stream>>>(q_lin, kv_lin, qn_g, qn_b, kn_g, kn_b,
                                              qtime, ktime, qvar, kvar, vemb, rope,
                                              q_nb, kfrag, vfrag);

    flash_mfma<<<512, blk, 0, stream>>>(q_nb, kfrag, vfrag, attn_h);

    gemm_o<<<dim3(16, 32), blk, 0, stream>>>(attn_h, owh, owl, o_b, out);
}

// Round 18
// 123.609 us; speedup vs baseline: 1.0874x; 1.0874x over previous
//
#include <hip/hip_runtime.h>
#include <math.h>

#define S 1024
#define DIMM 1024
#define G 4
#define HPG 4
#define HD 64
#define PW 32
#define SCALE 0.125f
#define LNEPS 1e-5f

typedef __bf16 bf16x8 __attribute__((ext_vector_type(8)));
typedef float  f32x4  __attribute__((ext_vector_type(4)));
typedef float  f32x16 __attribute__((ext_vector_type(16)));

// ------- fused f32->bf16 conversions + bias concat + RoPE cos/sin table ------
__global__ __launch_bounds__(256)
void cvt_all(const float* __restrict__ x, const float* __restrict__ kv,
             const float* __restrict__ qw, const float* __restrict__ kw,
             const float* __restrict__ vw, const float* __restrict__ ow,
             const float* __restrict__ kb, const float* __restrict__ vb_,
             __bf16* __restrict__ xh, __bf16* __restrict__ kvh,
             __bf16* __restrict__ qwh, __bf16* __restrict__ kvwh,
             __bf16* __restrict__ owh, __bf16* __restrict__ owl,
             float* __restrict__ kvbias, float2* __restrict__ rope) {
    if (blockIdx.x >= 5377) {
        const int idx = (blockIdx.x - 5377) * 256 + threadIdx.x;   // [0,16384)
        const int t = idx >> 4, i = idx & 15;
        const float theta = expf(-0.57564627324851f * (float)i);
        const float ang = (float)t * theta;
        rope[idx] = make_float2(cosf(ang), sinf(ang));
        return;
    }
    if (blockIdx.x == 5376) {
        kvbias[threadIdx.x]       = kb[threadIdx.x];
        kvbias[256 + threadIdx.x] = vb_[threadIdx.x];
        return;
    }
    long j = (long)blockIdx.x * 256 + threadIdx.x;
    const float* src; __bf16* dh; __bf16* dl = nullptr;
    if (j < 524288)            { src = x;  dh = xh; }
    else if ((j -= 524288) < 524288) { src = kv; dh = kvh; }
    else if ((j -= 524288) < 131072) { src = qw; dh = qwh; }
    else if ((j -= 131072) < 32768)  { src = kw; dh = kvwh; }
    else if ((j -= 32768) < 32768)   { src = vw; dh = kvwh + 262144; }
    else { j -= 32768; src = ow; dh = owh; dl = owl; }
    const float4 a = *(const float4*)(src + j * 8);
    const float4 b = *(const float4*)(src + j * 8 + 4);
    const float v[8] = {a.x, a.y, a.z, a.w, b.x, b.y, b.z, b.w};
    bf16x8 H;
    #pragma unroll
    for (int e = 0; e < 8; ++e) H[e] = (__bf16)v[e];
    *(bf16x8*)(dh + j * 8) = H;
    if (dl != nullptr) {
        bf16x8 L;
        #pragma unroll
        for (int e = 0; e < 8; ++e) L[e] = (__bf16)(v[e] - (float)H[e]);
        *(bf16x8*)(dl + j * 8) = L;
    }
}

// ---------------- bf16 MFMA GEMM helpers ----------------
__device__ __forceinline__ void gld_lds16(const __bf16* g, __bf16* lds) {
    __builtin_amdgcn_global_load_lds(
        (const __attribute__((address_space(1))) void*)g,
        (__attribute__((address_space(3))) void*)lds, 16, 0, 0);
}

// ---------------- fused q+kv projections (NB=64, 768 blocks) ----------------
__global__ __launch_bounds__(256)
void gemm_qkv(const __bf16* __restrict__ xh,  const __bf16* __restrict__ qwh,
              const float* __restrict__ qb,   __bf16* __restrict__ q_lin,
              const __bf16* __restrict__ kvh, const __bf16* __restrict__ kvwh,
              const float* __restrict__ kvb,  __bf16* __restrict__ kv_lin) {
    constexpr int K = 1024;
    __shared__ __bf16 Ahs[128][32];
    __shared__ __bf16 Whs[64][32];

    int bid = blockIdx.x;
    const __bf16 *A, *Wm; const float* bias; __bf16* C; int N, m0, n0;
    if (bid < 512) { A = xh;  Wm = qwh;  bias = qb;  C = q_lin;  N = 1024;
                     m0 = (bid >> 4) * 128; n0 = (bid & 15) * 64; }
    else { bid -= 512; A = kvh; Wm = kvwh; bias = kvb; C = kv_lin; N = 512;
           m0 = (bid >> 3) * 128; n0 = (bid & 7) * 64; }

    const int tid = threadIdx.x;
    const int w = tid >> 6, l = tid & 63;
    const int lr = l & 15, lh = l >> 4;
    const int wr = w >> 1, wc = w & 1;
    const int srow = l >> 2, scol = (l & 3) * 8;

    f32x4 acc[4][2];
    #pragma unroll
    for (int i = 0; i < 4; ++i)
        #pragma unroll
        for (int j = 0; j < 2; ++j) acc[i][j] = (f32x4){0.f, 0.f, 0.f, 0.f};

    const __bf16* Abp = A  + (size_t)(m0 + srow) * K + scol;
    const __bf16* Wbp = Wm + (size_t)(n0 + srow) * K + scol;

    for (int k0 = 0; k0 < K; k0 += 32) {
        #pragma unroll
        for (int c = 0; c < 2; ++c)
            gld_lds16(Abp + (size_t)(c * 4 + w) * 16 * K + k0, &Ahs[(c * 4 + w) * 16][0]);
        gld_lds16(Wbp + (size_t)w * 16 * K + k0, &Whs[w * 16][0]);
        __syncthreads();

        bf16x8 af[4], bfr[2];
        #pragma unroll
        for (int i = 0; i < 4; ++i) af[i] = *(const bf16x8*)&Ahs[wr * 64 + 16 * i + lr][lh * 8];
        #pragma unroll
        for (int j = 0; j < 2; ++j) bfr[j] = *(const bf16x8*)&Whs[wc * 32 + 16 * j + lr][lh * 8];
        #pragma unroll
        for (int i = 0; i < 4; ++i)
            #pragma unroll
            for (int j = 0; j < 2; ++j)
                acc[i][j] = __builtin_amdgcn_mfma_f32_16x16x32_bf16(af[i], bfr[j], acc[i][j], 0, 0, 0);
        __syncthreads();
    }

    float bv[2];
    #pragma unroll
    for (int j = 0; j < 2; ++j) bv[j] = bias[n0 + wc * 32 + 16 * j + lr];
    #pragma unroll
    for (int i = 0; i < 4; ++i) {
        const int mb = m0 + wr * 64 + 16 * i + 4 * lh;
        #pragma unroll
        for (int j = 0; j < 2; ++j) {
            const int n = n0 + wc * 32 + 16 * j + lr;
            #pragma unroll
            for (int r = 0; r < 4; ++r)
                C[(size_t)(mb + r) * N + n] = (__bf16)(acc[i][j][r] + bv[j]);
        }
    }
}

// ---------------- o-projection: 2-term W-split, N=64 tiles -------------------
__global__ __launch_bounds__(256)
void gemm_o(const __bf16* __restrict__ Ah, const __bf16* __restrict__ Wh,
            const __bf16* __restrict__ Wl, const float* __restrict__ bias,
            float* __restrict__ Cout) {
    constexpr int K = 1024, N = 1024;
    __shared__ __bf16 Ahs[128][32];
    __shared__ __bf16 Whs[64][32];
    __shared__ __bf16 Wls[64][32];

    const int tid = threadIdx.x;
    const int w = tid >> 6, l = tid & 63;
    const int lr = l & 15, lh = l >> 4;
    const int wr = w >> 1, wc = w & 1;
    const int m0 = blockIdx.y * 128, n0 = blockIdx.x * 64;
    const int srow = l >> 2, scol = (l & 3) * 8;

    f32x4 acc[4][2];
    #pragma unroll
    for (int i = 0; i < 4; ++i)
        #pragma unroll
        for (int j = 0; j < 2; ++j) acc[i][j] = (f32x4){0.f, 0.f, 0.f, 0.f};

    const __bf16* Abp = Ah + (size_t)(m0 + srow) * K + scol;
    const __bf16* Whp = Wh + (size_t)(n0 + srow) * K + scol;
    const __bf16* Wlp = Wl + (size_t)(n0 + srow) * K + scol;

    for (int k0 = 0; k0 < K; k0 += 32) {
        #pragma unroll
        for (int c = 0; c < 2; ++c)
            gld_lds16(Abp + (size_t)(c * 4 + w) * 16 * K + k0, &Ahs[(c * 4 + w) * 16][0]);
        gld_lds16(Whp + (size_t)w * 16 * K + k0, &Whs[w * 16][0]);
        gld_lds16(Wlp + (size_t)w * 16 * K + k0, &Wls[w * 16][0]);
        __syncthreads();

        bf16x8 af[4], bh[2], bl[2];
        #pragma unroll
        for (int i = 0; i < 4; ++i) af[i] = *(const bf16x8*)&Ahs[wr * 64 + 16 * i + lr][lh * 8];
        #pragma unroll
        for (int j = 0; j < 2; ++j) {
            bh[j] = *(const bf16x8*)&Whs[wc * 32 + 16 * j + lr][lh * 8];
            bl[j] = *(const bf16x8*)&Wls[wc * 32 + 16 * j + lr][lh * 8];
        }
        #pragma unroll
        for (int i = 0; i < 4; ++i)
            #pragma unroll
            for (int j = 0; j < 2; ++j) {
                acc[i][j] = __builtin_amdgcn_mfma_f32_16x16x32_bf16(af[i], bh[j], acc[i][j], 0, 0, 0);
                acc[i][j] = __builtin_amdgcn_mfma_f32_16x16x32_bf16(af[i], bl[j], acc[i][j], 0, 0, 0);
            }
        __syncthreads();
    }

    float bv[2];
    #pragma unroll
    for (int j = 0; j < 2; ++j) bv[j] = bias[n0 + wc * 32 + 16 * j + lr];
    #pragma unroll
    for (int i = 0; i < 4; ++i) {
        const int mb = m0 + wr * 64 + 16 * i + 4 * lh;
        #pragma unroll
        for (int j = 0; j < 2; ++j) {
            const int n = n0 + wc * 32 + 16 * j + lr;
            #pragma unroll
            for (int r = 0; r < 4; ++r)
                Cout[(size_t)(mb + r) * N + n] = acc[i][j][r] + bv[j];
        }
    }
}

// ---------------- wave helpers ----------------
__device__ inline float wave64_sum(float v) {
    #pragma unroll
    for (int off = 32; off >= 1; off >>= 1) v += __shfl_xor(v, off);
    return v;
}

// ---------------- fused transforms (RoPE via table; Q pre-scaled by SC2) -----
__global__ __launch_bounds__(256)
void transforms_all(const __bf16* __restrict__ q_lin, const __bf16* __restrict__ kv_lin,
                    const float* __restrict__ qn_g, const float* __restrict__ qn_b,
                    const float* __restrict__ kn_g, const float* __restrict__ kn_b,
                    const int* __restrict__ qtime, const int* __restrict__ ktime,
                    const int* __restrict__ qvar, const int* __restrict__ kvar,
                    const float* __restrict__ var_emb, const float2* __restrict__ rope,
                    __bf16* __restrict__ q_nb, __bf16* __restrict__ kfrag,
                    __bf16* __restrict__ vfrag) {
    __shared__ float T[64][65];
    const int bid = blockIdx.x;
    const int lane = threadIdx.x & 63;
    constexpr float SC2 = 0.125f * 1.4426950408889634f;   // 0.18033688

    if (bid < 16384) {
        const int row = bid * 4 + (threadIdx.x >> 6);
        const int s   = row & (S - 1);
        const int bgh = row >> 10;
        const int b   = bgh >> 4;
        const int gh  = bgh & 15;
        float x = (float)q_lin[(size_t)(b * S + s) * DIMM + gh * HD + lane];
        const float m = wave64_sum(x) * (1.0f / 64.0f);
        const float d = x - m;
        const float v = wave64_sum(d * d) * (1.0f / 64.0f);
        float y = d * rsqrtf(v + LNEPS) * qn_g[lane] + qn_b[lane];
        const float partner = __shfl_xor(y, 1);
        if (lane < PW) {
            const float2 cs = rope[qtime[b * S + s] * 16 + (lane >> 1)];
            y = cs.x * y + cs.y * ((lane & 1) ? partner : -partner);
        }
        __bf16* qrow = q_nb + (size_t)row * 80;
        qrow[lane] = (__bf16)(y * SC2);
        if (lane < 16) {
            const int qv = qvar[b * S + s];
            float ex = 0.0f;
            if (lane < 8) {
                const float dw = var_emb[16 + gh] - var_emb[gh];
                ex = (qv == lane) ? 8.0f * dw * SC2 : 0.0f;
            } else if (lane == 8) {
                ex = (8.0f * var_emb[gh] - 69.31471805599453f) * SC2;
            }
            qrow[64 + lane] = (__bf16)ex;
        }
    } else if (bid < 20480) {
        const int row = (bid - 16384) * 4 + (threadIdx.x >> 6);
        const int s   = row & (S - 1);
        const int bg  = row >> 10;
        const int b   = bg >> 2;
        const int g   = bg & 3;
        float x = (float)kv_lin[(size_t)(b * S + s) * 512 + g * HD + lane];
        const float m = wave64_sum(x) * (1.0f / 64.0f);
        const float d = x - m;
        const float v = wave64_sum(d * d) * (1.0f / 64.0f);
        float y = d * rsqrtf(v + LNEPS) * kn_g[lane] + kn_b[lane];
        const float partner = __shfl_xor(y, 1);
        if (lane < PW) {
            const float2 cs = rope[ktime[b * S + s] * 16 + (lane >> 1)];
            y = cs.x * y + cs.y * ((lane & 1) ? partner : -partner);
        }
        const int kt = s >> 6, ks = (s >> 5) & 1, lq = s & 31;
        const size_t tb = (size_t)((bg * 16 + kt) * 10 + ks * 5);
        kfrag[(tb + (lane >> 4)) * 512 + ((lane >> 3) & 1) * 256 + lq * 8 + (lane & 7)]
            = (__bf16)y;
        if (lane < 16) {
            const int kvv = kvar[b * S + s];
            const int hh = lane >> 3, e = lane & 7;
            float ex;
            if (hh == 0) ex = (kvv == e) ? 1.0f : 0.0f;
            else         ex = (e == 0) ? 1.0f : 0.0f;
            kfrag[(tb + 4) * 512 + hh * 256 + lq * 8 + e] = (__bf16)ex;
        }
    } else {
        const int vb = bid - 20480;
        const int bg = vb >> 4;
        const int kt = vb & 15;
        const int b = bg >> 2, g = bg & 3;
        const int tx = threadIdx.x & 63, ty = threadIdx.x >> 6;
        const __bf16* src = kv_lin + ((size_t)(b * S) + kt * 64) * 512 + 256 + g * HD;
        #pragma unroll
        for (int i = 0; i < 16; ++i) {
            const int kl = ty + 4 * i;
            T[kl][tx] = (float)src[(size_t)kl * 512 + tx];
        }
        __syncthreads();
        __bf16* dst = vfrag + (size_t)bg * 65536 + (size_t)kt * 4096;
        #pragma unroll
        for (int half = 0; half < 2; ++half) {
            const int c  = half * 256 + threadIdx.x;
            const int lq = c & 31;
            const int h  = (c >> 5) & 1;
            const int kc = (c >> 6) & 1;
            const int ks = (c >> 7) & 1;
            const int t  = (c >> 8) & 1;
            const int kl = 32 * ks + 16 * kc + 8 * h;
            const int d  = 32 * t + lq;
            bf16x8 o;
            #pragma unroll
            for (int e = 0; e < 8; ++e) o[e] = (__bf16)T[kl + e][d];
            *(bf16x8*)(dst + ((size_t)((t * 2 + ks) * 2 + kc) * 2 + h) * 256 + lq * 8) = o;
        }
    }
}

// ---------------- flash attention: bias-in-MFMA + pre-scaled Q ----------------
// P = exp2(st); pointer-advance addressing. 32 q-rows/wave, K-split x2.
// __launch_bounds__(256,2) is the measured optimum; reg-budget lessons:
// (256,3) shaves regs + scratch (R15); (256,4) hard-spills (R12);
// 64q/wave exceeds the 256-reg unified budget and spills (R17).
__global__ __launch_bounds__(256, 2)
void flash_mfma(const __bf16* __restrict__ q_n, const __bf16* __restrict__ kfrag,
                const __bf16* __restrict__ vfrag, __bf16* __restrict__ attn_h) {
    __shared__ f32x4 Osh[2][8][64];
    __shared__ float lsh[2][64];

    // XCD-aware swizzle: 1024 blocks, 8 XCDs, 128 contiguous per XCD
    const int orig = blockIdx.x;
    const int bid  = (orig & 7) * 128 + (orig >> 3);

    const int tid = threadIdx.x;
    const int w = tid >> 6, l = tid & 63;
    const int lq = l & 31;
    const int h  = l >> 5;
    const int qhalf = w >> 1, khalf = w & 1;
    const int qb  = bid & 15;
    const int bgh = bid >> 4;
    const int b = bgh >> 4, gh = bgh & 15;
    const int bg = bgh >> 2;
    const int q0 = qb * 64 + qhalf * 32;
    const int ktbeg = khalf * 8;

    // Q B-frags (80-dim rows, pre-scaled): qf[4] = bias dims
    const __bf16* qbase = q_n + ((size_t)bgh * S + q0 + lq) * 80 + 8 * h;
    bf16x8 qf[5];
    #pragma unroll
    for (int dc = 0; dc < 4; ++dc) qf[dc] = *(const bf16x8*)(qbase + 16 * dc);
    qf[4] = *(const bf16x8*)(qbase + 64);

    // per-tile advancing base pointers (lane offset folded in)
    const __bf16* kptr = kfrag + (size_t)bg * 81920 + (size_t)l * 8
                       + (size_t)ktbeg * 5120;
    const __bf16* vptr = vfrag + (size_t)bg * 65536 + (size_t)l * 8
                       + (size_t)ktbeg * 4096;

    f32x16 OT[2];
    #pragma unroll
    for (int t = 0; t < 2; ++t)
        #pragma unroll
        for (int r = 0; r < 16; ++r) OT[t][r] = 0.0f;
    float lrun = 0.0f;

    // preload K tile ktbeg (10 chunks)
    bf16x8 kf[2][5];
    #pragma unroll
    for (int ks = 0; ks < 2; ++ks)
        #pragma unroll
        for (int dc = 0; dc < 5; ++dc)
            kf[ks][dc] = *(const bf16x8*)(kptr + (size_t)(ks * 5 + dc) * 512);
    kptr += 5120;

    for (int ti = 0; ti < 8; ++ti) {
        // V A-frags for current tile (8 x 1KB from vptr)
        bf16x8 vf[2][2][2];
        #pragma unroll
        for (int t = 0; t < 2; ++t)
            #pragma unroll
            for (int ks = 0; ks < 2; ++ks)
                #pragma unroll
                for (int kc = 0; kc < 2; ++kc)
                    vf[t][ks][kc] = *(const bf16x8*)
                        (vptr + (size_t)((t * 2 + ks) * 2 + kc) * 512);
        vptr += 4096;

        // swapped QK^T over 80 dims: scale+bias already inside accumulator
        f32x16 st[2];
        __builtin_amdgcn_s_setprio(1);
        #pragma unroll
        for (int ks = 0; ks < 2; ++ks) {
            f32x16 acc;
            #pragma unroll
            for (int r = 0; r < 16; ++r) acc[r] = 0.0f;
            #pragma unroll
            for (int dc = 0; dc < 5; ++dc)
                acc = __builtin_amdgcn_mfma_f32_32x32x16_bf16(kf[ks][dc], qf[dc], acc, 0, 0, 0);
            st[ks] = acc;
        }
        __builtin_amdgcn_s_setprio(0);

        // prefetch next K tile
        if (ti < 7) {
            #pragma unroll
            for (int ks = 0; ks < 2; ++ks)
                #pragma unroll
                for (int dc = 0; dc < 5; ++dc)
                    kf[ks][dc] = *(const bf16x8*)(kptr + (size_t)(ks * 5 + dc) * 512);
            kptr += 5120;
        }

        // P = exp2(st): no scale, no bias, no branch
        unsigned int u[2][8];
        #pragma unroll
        for (int ks = 0; ks < 2; ++ks)
            #pragma unroll
            for (int jj = 0; jj < 8; ++jj) {
                const float p0 = exp2f(st[ks][2 * jj]);
                const float p1 = exp2f(st[ks][2 * jj + 1]);
                lrun += p0 + p1;
                asm("v_cvt_pk_bf16_f32 %0, %1, %2" : "=v"(u[ks][jj]) : "v"(p0), "v"(p1));
            }

        // P redistribution via permlane32_swap -> B-frag words
        uint4 F[2][2];
        #pragma unroll
        for (int ks = 0; ks < 2; ++ks) {
            unsigned a0 = u[ks][0], b0 = u[ks][2];
            unsigned a1 = u[ks][1], b1 = u[ks][3];
            asm("v_permlane32_swap_b32 %0, %1" : "+v"(a0), "+v"(b0));
            asm("v_permlane32_swap_b32 %0, %1" : "+v"(a1), "+v"(b1));
            F[ks][0] = make_uint4(a0, a1, b0, b1);
            unsigned a2 = u[ks][4], b2 = u[ks][6];
            unsigned a3 = u[ks][5], b3 = u[ks][7];
            asm("v_permlane32_swap_b32 %0, %1" : "+v"(a2), "+v"(b2));
            asm("v_permlane32_swap_b32 %0, %1" : "+v"(a3), "+v"(b3));
            F[ks][1] = make_uint4(a2, a3, b2, b3);
        }

        // PV
        __builtin_amdgcn_s_setprio(1);
        #pragma unroll
        for (int t = 0; t < 2; ++t)
            #pragma unroll
            for (int ks = 0; ks < 2; ++ks)
                #pragma unroll
                for (int kc = 0; kc < 2; ++kc)
                    OT[t] = __builtin_amdgcn_mfma_f32_32x32x16_bf16(
                        vf[t][ks][kc], __builtin_bit_cast(bf16x8, F[ks][kc]), OT[t], 0, 0, 0);
        __builtin_amdgcn_s_setprio(0);
    }

    // ---- merge the two K-halves: pure sums (static softmax reference) ----
    if (khalf) {
        #pragma unroll
        for (int t = 0; t < 2; ++t)
            #pragma unroll
            for (int c = 0; c < 4; ++c)
                Osh[qhalf][t * 4 + c][l] = (f32x4){OT[t][4 * c], OT[t][4 * c + 1],
                                                   OT[t][4 * c + 2], OT[t][4 * c + 3]};
        lsh[qhalf][l] = lrun;
    }
    __syncthreads();
    if (khalf) return;

    #pragma unroll
    for (int t = 0; t < 2; ++t)
        #pragma unroll
        for (int c = 0; c < 4; ++c) {
            const f32x4 o = Osh[qhalf][t * 4 + c][l];
            OT[t][4 * c]     += o[0];
            OT[t][4 * c + 1] += o[1];
            OT[t][4 * c + 2] += o[2];
            OT[t][4 * c + 3] += o[3];
        }
    lrun += lsh[qhalf][l];
    lrun += __shfl_xor(lrun, 32);
    const float linv = 1.0f / lrun;

    __bf16* oh = attn_h + (size_t)(b * S + q0 + lq) * DIMM + gh * HD;
    #pragma unroll
    for (int t = 0; t < 2; ++t)
        #pragma unroll
        for (int j = 0; j < 4; ++j) {
            const int d0 = 32 * t + 8 * j + 4 * h;
            unsigned short hv[4];
            #pragma unroll
            for (int c = 0; c < 4; ++c)
                hv[c] = __builtin_bit_cast(unsigned short, (__bf16)(OT[t][4 * j + c] * linv));
            *(ushort4*)(oh + d0) = make_ushort4(hv[0], hv[1], hv[2], hv[3]);
        }
}

extern "C" void kernel_launch(void* const* d_in, const int* in_sizes, int n_in,
                              void* d_out, int out_size, void* d_ws, size_t ws_size,
                              hipStream_t stream) {
    const float* x     = (const float*)d_in[0];
    const float* kv    = (const float*)d_in[1];
    const float* q_w   = (const float*)d_in[2];
    const float* q_b   = (const float*)d_in[3];
    const float* k_w   = (const float*)d_in[4];
    const float* k_b   = (const float*)d_in[5];
    const float* v_w   = (const float*)d_in[6];
    const float* v_b   = (const float*)d_in[7];
    const float* o_w   = (const float*)d_in[8];
    const float* o_b   = (const float*)d_in[9];
    const float* qn_g  = (const float*)d_in[10];
    const float* qn_b  = (const float*)d_in[11];
    const float* kn_g  = (const float*)d_in[12];
    const float* kn_b  = (const float*)d_in[13];
    const float* vemb  = (const float*)d_in[14];
    const int*   qvar  = (const int*)d_in[15];
    const int*   kvar  = (const int*)d_in[16];
    const int*   qtime = (const int*)d_in[17];
    const int*   ktime = (const int*)d_in[18];
    float* out = (float*)d_out;
    char*  W   = (char*)d_ws;

    const size_t MB = 1u << 20;
    __bf16* xh     = (__bf16*)(W);                   // 0-8   -> attn_h
    __bf16* kvh    = (__bf16*)(W + 8 * MB);          // 8-16  -> q_nb
    __bf16* q_nb   = (__bf16*)(W + 8 * MB);          // 8-18  (80-dim rows)
    __bf16* q_lin  = (__bf16*)(W + 18 * MB);         // 18-26
    __bf16* kv_lin = (__bf16*)(W + 26 * MB);         // 26-30
    __bf16* qwh    = (__bf16*)(W + 30 * MB);         // 30-32
    __bf16* kvwh   = (__bf16*)(W + 32 * MB);         // 32-33
    __bf16* kfrag  = (__bf16*)(W + 33 * MB);         // 33-35.5
    __bf16* vfrag  = (__bf16*)(W + 35 * MB + MB / 2);// 35.5-37.5
    __bf16* owh    = (__bf16*)(W + 37 * MB + MB / 2);// 37.5-39.5
    __bf16* owl    = (__bf16*)(W + 39 * MB + MB / 2);// 39.5-41.5
    float*  kvb    = (float*)(W + 42 * MB);          // 2 KB
    float2* rope   = (float2*)(W + 42 * MB + 4096);  // 128 KB
    __bf16* attn_h = xh;

    dim3 blk(256);

    cvt_all<<<5441, blk, 0, stream>>>(x, kv, q_w, k_w, v_w, o_w, k_b, v_b,
                                      xh, kvh, qwh, kvwh, owh, owl, kvb, rope);

    gemm_qkv<<<768, blk, 0, stream>>>(xh, qwh, q_b, q_lin, kvh, kvwh, kvb, kv_lin);

    transforms_all<<<20736, blk, 0, stream>>>(q_lin, kv_lin, qn_g, qn_b, kn_g, kn_b,
                                              qtime, ktime, qvar, kvar, vemb, rope,
                                              q_nb, kfrag, vfrag);

    flash_mfma<<<1024, blk, 0, stream>>>(q_nb, kfrag, vfrag, attn_h);

    gemm_o<<<dim3(16, 32), blk, 0, stream>>>(attn_h, owh, owl, o_b, out);
}

// Round 19
// 122.459 us; speedup vs baseline: 1.0976x; 1.0094x over previous
//
#include <hip/hip_runtime.h>
#include <math.h>

#define S 1024
#define DIMM 1024
#define G 4
#define HPG 4
#define HD 64
#define PW 32
#define SCALE 0.125f
#define LNEPS 1e-5f

typedef __bf16 bf16x8 __attribute__((ext_vector_type(8)));
typedef float  f32x4  __attribute__((ext_vector_type(4)));
typedef float  f32x16 __attribute__((ext_vector_type(16)));

// ------- fused f32->bf16 conversions + bias concat + RoPE cos/sin table ------
__global__ __launch_bounds__(256)
void cvt_all(const float* __restrict__ x, const float* __restrict__ kv,
             const float* __restrict__ qw, const float* __restrict__ kw,
             const float* __restrict__ vw, const float* __restrict__ ow,
             const float* __restrict__ kb, const float* __restrict__ vb_,
             __bf16* __restrict__ xh, __bf16* __restrict__ kvh,
             __bf16* __restrict__ qwh, __bf16* __restrict__ kvwh,
             __bf16* __restrict__ owh, __bf16* __restrict__ owl,
             float* __restrict__ kvbias, float2* __restrict__ rope) {
    if (blockIdx.x >= 5377) {
        const int idx = (blockIdx.x - 5377) * 256 + threadIdx.x;   // [0,16384)
        const int t = idx >> 4, i = idx & 15;
        const float theta = expf(-0.57564627324851f * (float)i);
        const float ang = (float)t * theta;
        rope[idx] = make_float2(cosf(ang), sinf(ang));
        return;
    }
    if (blockIdx.x == 5376) {
        kvbias[threadIdx.x]       = kb[threadIdx.x];
        kvbias[256 + threadIdx.x] = vb_[threadIdx.x];
        return;
    }
    long j = (long)blockIdx.x * 256 + threadIdx.x;
    const float* src; __bf16* dh; __bf16* dl = nullptr;
    if (j < 524288)            { src = x;  dh = xh; }
    else if ((j -= 524288) < 524288) { src = kv; dh = kvh; }
    else if ((j -= 524288) < 131072) { src = qw; dh = qwh; }
    else if ((j -= 131072) < 32768)  { src = kw; dh = kvwh; }
    else if ((j -= 32768) < 32768)   { src = vw; dh = kvwh + 262144; }
    else { j -= 32768; src = ow; dh = owh; dl = owl; }
    const float4 a = *(const float4*)(src + j * 8);
    const float4 b = *(const float4*)(src + j * 8 + 4);
    const float v[8] = {a.x, a.y, a.z, a.w, b.x, b.y, b.z, b.w};
    bf16x8 H;
    #pragma unroll
    for (int e = 0; e < 8; ++e) H[e] = (__bf16)v[e];
    *(bf16x8*)(dh + j * 8) = H;
    if (dl != nullptr) {
        bf16x8 L;
        #pragma unroll
        for (int e = 0; e < 8; ++e) L[e] = (__bf16)(v[e] - (float)H[e]);
        *(bf16x8*)(dl + j * 8) = L;
    }
}

// ---------------- bf16 MFMA GEMM helpers ----------------
__device__ __forceinline__ void gld_lds16(const __bf16* g, __bf16* lds) {
    __builtin_amdgcn_global_load_lds(
        (const __attribute__((address_space(1))) void*)g,
        (__attribute__((address_space(3))) void*)lds, 16, 0, 0);
}

// ---------------- fused q+kv projections (NB=64, 768 blocks) ----------------
__global__ __launch_bounds__(256)
void gemm_qkv(const __bf16* __restrict__ xh,  const __bf16* __restrict__ qwh,
              const float* __restrict__ qb,   __bf16* __restrict__ q_lin,
              const __bf16* __restrict__ kvh, const __bf16* __restrict__ kvwh,
              const float* __restrict__ kvb,  __bf16* __restrict__ kv_lin) {
    constexpr int K = 1024;
    __shared__ __bf16 Ahs[128][32];
    __shared__ __bf16 Whs[64][32];

    int bid = blockIdx.x;
    const __bf16 *A, *Wm; const float* bias; __bf16* C; int N, m0, n0;
    if (bid < 512) { A = xh;  Wm = qwh;  bias = qb;  C = q_lin;  N = 1024;
                     m0 = (bid >> 4) * 128; n0 = (bid & 15) * 64; }
    else { bid -= 512; A = kvh; Wm = kvwh; bias = kvb; C = kv_lin; N = 512;
           m0 = (bid >> 3) * 128; n0 = (bid & 7) * 64; }

    const int tid = threadIdx.x;
    const int w = tid >> 6, l = tid & 63;
    const int lr = l & 15, lh = l >> 4;
    const int wr = w >> 1, wc = w & 1;
    const int srow = l >> 2, scol = (l & 3) * 8;

    f32x4 acc[4][2];
    #pragma unroll
    for (int i = 0; i < 4; ++i)
        #pragma unroll
        for (int j = 0; j < 2; ++j) acc[i][j] = (f32x4){0.f, 0.f, 0.f, 0.f};

    const __bf16* Abp = A  + (size_t)(m0 + srow) * K + scol;
    const __bf16* Wbp = Wm + (size_t)(n0 + srow) * K + scol;

    for (int k0 = 0; k0 < K; k0 += 32) {
        #pragma unroll
        for (int c = 0; c < 2; ++c)
            gld_lds16(Abp + (size_t)(c * 4 + w) * 16 * K + k0, &Ahs[(c * 4 + w) * 16][0]);
        gld_lds16(Wbp + (size_t)w * 16 * K + k0, &Whs[w * 16][0]);
        __syncthreads();

        bf16x8 af[4], bfr[2];
        #pragma unroll
        for (int i = 0; i < 4; ++i) af[i] = *(const bf16x8*)&Ahs[wr * 64 + 16 * i + lr][lh * 8];
        #pragma unroll
        for (int j = 0; j < 2; ++j) bfr[j] = *(const bf16x8*)&Whs[wc * 32 + 16 * j + lr][lh * 8];
        #pragma unroll
        for (int i = 0; i < 4; ++i)
            #pragma unroll
            for (int j = 0; j < 2; ++j)
                acc[i][j] = __builtin_amdgcn_mfma_f32_16x16x32_bf16(af[i], bfr[j], acc[i][j], 0, 0, 0);
        __syncthreads();
    }

    float bv[2];
    #pragma unroll
    for (int j = 0; j < 2; ++j) bv[j] = bias[n0 + wc * 32 + 16 * j + lr];
    #pragma unroll
    for (int i = 0; i < 4; ++i) {
        const int mb = m0 + wr * 64 + 16 * i + 4 * lh;
        #pragma unroll
        for (int j = 0; j < 2; ++j) {
            const int n = n0 + wc * 32 + 16 * j + lr;
            #pragma unroll
            for (int r = 0; r < 4; ++r)
                C[(size_t)(mb + r) * N + n] = (__bf16)(acc[i][j][r] + bv[j]);
        }
    }
}

// ---------------- o-projection: 2-term W-split, N=64 tiles -------------------
__global__ __launch_bounds__(256)
void gemm_o(const __bf16* __restrict__ Ah, const __bf16* __restrict__ Wh,
            const __bf16* __restrict__ Wl, const float* __restrict__ bias,
            float* __restrict__ Cout) {
    constexpr int K = 1024, N = 1024;
    __shared__ __bf16 Ahs[128][32];
    __shared__ __bf16 Whs[64][32];
    __shared__ __bf16 Wls[64][32];

    const int tid = threadIdx.x;
    const int w = tid >> 6, l = tid & 63;
    const int lr = l & 15, lh = l >> 4;
    const int wr = w >> 1, wc = w & 1;
    const int m0 = blockIdx.y * 128, n0 = blockIdx.x * 64;
    const int srow = l >> 2, scol = (l & 3) * 8;

    f32x4 acc[4][2];
    #pragma unroll
    for (int i = 0; i < 4; ++i)
        #pragma unroll
        for (int j = 0; j < 2; ++j) acc[i][j] = (f32x4){0.f, 0.f, 0.f, 0.f};

    const __bf16* Abp = Ah + (size_t)(m0 + srow) * K + scol;
    const __bf16* Whp = Wh + (size_t)(n0 + srow) * K + scol;
    const __bf16* Wlp = Wl + (size_t)(n0 + srow) * K + scol;

    for (int k0 = 0; k0 < K; k0 += 32) {
        #pragma unroll
        for (int c = 0; c < 2; ++c)
            gld_lds16(Abp + (size_t)(c * 4 + w) * 16 * K + k0, &Ahs[(c * 4 + w) * 16][0]);
        gld_lds16(Whp + (size_t)w * 16 * K + k0, &Whs[w * 16][0]);
        gld_lds16(Wlp + (size_t)w * 16 * K + k0, &Wls[w * 16][0]);
        __syncthreads();

        bf16x8 af[4], bh[2], bl[2];
        #pragma unroll
        for (int i = 0; i < 4; ++i) af[i] = *(const bf16x8*)&Ahs[wr * 64 + 16 * i + lr][lh * 8];
        #pragma unroll
        for (int j = 0; j < 2; ++j) {
            bh[j] = *(const bf16x8*)&Whs[wc * 32 + 16 * j + lr][lh * 8];
            bl[j] = *(const bf16x8*)&Wls[wc * 32 + 16 * j + lr][lh * 8];
        }
        #pragma unroll
        for (int i = 0; i < 4; ++i)
            #pragma unroll
            for (int j = 0; j < 2; ++j) {
                acc[i][j] = __builtin_amdgcn_mfma_f32_16x16x32_bf16(af[i], bh[j], acc[i][j], 0, 0, 0);
                acc[i][j] = __builtin_amdgcn_mfma_f32_16x16x32_bf16(af[i], bl[j], acc[i][j], 0, 0, 0);
            }
        __syncthreads();
    }

    float bv[2];
    #pragma unroll
    for (int j = 0; j < 2; ++j) bv[j] = bias[n0 + wc * 32 + 16 * j + lr];
    #pragma unroll
    for (int i = 0; i < 4; ++i) {
        const int mb = m0 + wr * 64 + 16 * i + 4 * lh;
        #pragma unroll
        for (int j = 0; j < 2; ++j) {
            const int n = n0 + wc * 32 + 16 * j + lr;
            #pragma unroll
            for (int r = 0; r < 4; ++r)
                Cout[(size_t)(mb + r) * N + n] = acc[i][j][r] + bv[j];
        }
    }
}

// ---------------- wave helpers ----------------
__device__ inline float wave64_sum(float v) {
    #pragma unroll
    for (int off = 32; off >= 1; off >>= 1) v += __shfl_xor(v, off);
    return v;
}

// ---------------- fused transforms (RoPE via table; Q pre-scaled by SC2) -----
__global__ __launch_bounds__(256)
void transforms_all(const __bf16* __restrict__ q_lin, const __bf16* __restrict__ kv_lin,
                    const float* __restrict__ qn_g, const float* __restrict__ qn_b,
                    const float* __restrict__ kn_g, const float* __restrict__ kn_b,
                    const int* __restrict__ qtime, const int* __restrict__ ktime,
                    const int* __restrict__ qvar, const int* __restrict__ kvar,
                    const float* __restrict__ var_emb, const float2* __restrict__ rope,
                    __bf16* __restrict__ q_nb, __bf16* __restrict__ kfrag,
                    __bf16* __restrict__ vfrag) {
    __shared__ float T[64][65];
    const int bid = blockIdx.x;
    const int lane = threadIdx.x & 63;
    constexpr float SC2 = 0.125f * 1.4426950408889634f;   // 0.18033688

    if (bid < 16384) {
        const int row = bid * 4 + (threadIdx.x >> 6);
        const int s   = row & (S - 1);
        const int bgh = row >> 10;
        const int b   = bgh >> 4;
        const int gh  = bgh & 15;
        float x = (float)q_lin[(size_t)(b * S + s) * DIMM + gh * HD + lane];
        const float m = wave64_sum(x) * (1.0f / 64.0f);
        const float d = x - m;
        const float v = wave64_sum(d * d) * (1.0f / 64.0f);
        float y = d * rsqrtf(v + LNEPS) * qn_g[lane] + qn_b[lane];
        const float partner = __shfl_xor(y, 1);
        if (lane < PW) {
            const float2 cs = rope[qtime[b * S + s] * 16 + (lane >> 1)];
            y = cs.x * y + cs.y * ((lane & 1) ? partner : -partner);
        }
        __bf16* qrow = q_nb + (size_t)row * 80;
        qrow[lane] = (__bf16)(y * SC2);
        if (lane < 16) {
            const int qv = qvar[b * S + s];
            float ex = 0.0f;
            if (lane < 8) {
                const float dw = var_emb[16 + gh] - var_emb[gh];
                ex = (qv == lane) ? 8.0f * dw * SC2 : 0.0f;
            } else if (lane == 8) {
                ex = (8.0f * var_emb[gh] - 69.31471805599453f) * SC2;
            }
            qrow[64 + lane] = (__bf16)ex;
        }
    } else if (bid < 20480) {
        const int row = (bid - 16384) * 4 + (threadIdx.x >> 6);
        const int s   = row & (S - 1);
        const int bg  = row >> 10;
        const int b   = bg >> 2;
        const int g   = bg & 3;
        float x = (float)kv_lin[(size_t)(b * S + s) * 512 + g * HD + lane];
        const float m = wave64_sum(x) * (1.0f / 64.0f);
        const float d = x - m;
        const float v = wave64_sum(d * d) * (1.0f / 64.0f);
        float y = d * rsqrtf(v + LNEPS) * kn_g[lane] + kn_b[lane];
        const float partner = __shfl_xor(y, 1);
        if (lane < PW) {
            const float2 cs = rope[ktime[b * S + s] * 16 + (lane >> 1)];
            y = cs.x * y + cs.y * ((lane & 1) ? partner : -partner);
        }
        const int kt = s >> 6, ks = (s >> 5) & 1, lq = s & 31;
        const size_t tb = (size_t)((bg * 16 + kt) * 10 + ks * 5);
        kfrag[(tb + (lane >> 4)) * 512 + ((lane >> 3) & 1) * 256 + lq * 8 + (lane & 7)]
            = (__bf16)y;
        if (lane < 16) {
            const int kvv = kvar[b * S + s];
            const int hh = lane >> 3, e = lane & 7;
            float ex;
            if (hh == 0) ex = (kvv == e) ? 1.0f : 0.0f;
            else         ex = (e == 0) ? 1.0f : 0.0f;
            kfrag[(tb + 4) * 512 + hh * 256 + lq * 8 + e] = (__bf16)ex;
        }
    } else {
        const int vb = bid - 20480;
        const int bg = vb >> 4;
        const int kt = vb & 15;
        const int b = bg >> 2, g = bg & 3;
        const int tx = threadIdx.x & 63, ty = threadIdx.x >> 6;
        const __bf16* src = kv_lin + ((size_t)(b * S) + kt * 64) * 512 + 256 + g * HD;
        #pragma unroll
        for (int i = 0; i < 16; ++i) {
            const int kl = ty + 4 * i;
            T[kl][tx] = (float)src[(size_t)kl * 512 + tx];
        }
        __syncthreads();
        __bf16* dst = vfrag + (size_t)bg * 65536 + (size_t)kt * 4096;
        #pragma unroll
        for (int half = 0; half < 2; ++half) {
            const int c  = half * 256 + threadIdx.x;
            const int lq = c & 31;
            const int h  = (c >> 5) & 1;
            const int kc = (c >> 6) & 1;
            const int ks = (c >> 7) & 1;
            const int t  = (c >> 8) & 1;
            const int kl = 32 * ks + 16 * kc + 8 * h;
            const int d  = 32 * t + lq;
            bf16x8 o;
            #pragma unroll
            for (int e = 0; e < 8; ++e) o[e] = (__bf16)T[kl + e][d];
            *(bf16x8*)(dst + ((size_t)((t * 2 + ks) * 2 + kc) * 2 + h) * 256 + lq * 8) = o;
        }
    }
}

// ---------------- flash attention: bias-in-MFMA + pre-scaled Q ----------------
// P = exp2(st); 4-way partial lrun accumulators (breaks 16-deep serial chain).
// __launch_bounds__(256,2) is the measured optimum (R12/R15/R17 spill map).
__global__ __launch_bounds__(256, 2)
void flash_mfma(const __bf16* __restrict__ q_n, const __bf16* __restrict__ kfrag,
                const __bf16* __restrict__ vfrag, __bf16* __restrict__ attn_h) {
    __shared__ f32x4 Osh[2][8][64];
    __shared__ float lsh[2][64];

    // XCD-aware swizzle: 1024 blocks, 8 XCDs, 128 contiguous per XCD
    const int orig = blockIdx.x;
    const int bid  = (orig & 7) * 128 + (orig >> 3);

    const int tid = threadIdx.x;
    const int w = tid >> 6, l = tid & 63;
    const int lq = l & 31;
    const int h  = l >> 5;
    const int qhalf = w >> 1, khalf = w & 1;
    const int qb  = bid & 15;
    const int bgh = bid >> 4;
    const int b = bgh >> 4, gh = bgh & 15;
    const int bg = bgh >> 2;
    const int q0 = qb * 64 + qhalf * 32;
    const int ktbeg = khalf * 8;

    // Q B-frags (80-dim rows, pre-scaled): qf[4] = bias dims
    const __bf16* qbase = q_n + ((size_t)bgh * S + q0 + lq) * 80 + 8 * h;
    bf16x8 qf[5];
    #pragma unroll
    for (int dc = 0; dc < 4; ++dc) qf[dc] = *(const bf16x8*)(qbase + 16 * dc);
    qf[4] = *(const bf16x8*)(qbase + 64);

    // per-tile advancing base pointers (lane offset folded in)
    const __bf16* kptr = kfrag + (size_t)bg * 81920 + (size_t)l * 8
                       + (size_t)ktbeg * 5120;
    const __bf16* vptr = vfrag + (size_t)bg * 65536 + (size_t)l * 8
                       + (size_t)ktbeg * 4096;

    f32x16 OT[2];
    #pragma unroll
    for (int t = 0; t < 2; ++t)
        #pragma unroll
        for (int r = 0; r < 16; ++r) OT[t][r] = 0.0f;
    float lp[4] = {0.0f, 0.0f, 0.0f, 0.0f};   // 4-way partial row-sums

    // preload K tile ktbeg (10 chunks)
    bf16x8 kf[2][5];
    #pragma unroll
    for (int ks = 0; ks < 2; ++ks)
        #pragma unroll
        for (int dc = 0; dc < 5; ++dc)
            kf[ks][dc] = *(const bf16x8*)(kptr + (size_t)(ks * 5 + dc) * 512);
    kptr += 5120;

    for (int ti = 0; ti < 8; ++ti) {
        // V A-frags for current tile (8 x 1KB from vptr)
        bf16x8 vf[2][2][2];
        #pragma unroll
        for (int t = 0; t < 2; ++t)
            #pragma unroll
            for (int ks = 0; ks < 2; ++ks)
                #pragma unroll
                for (int kc = 0; kc < 2; ++kc)
                    vf[t][ks][kc] = *(const bf16x8*)
                        (vptr + (size_t)((t * 2 + ks) * 2 + kc) * 512);
        vptr += 4096;

        // swapped QK^T over 80 dims: scale+bias already inside accumulator
        f32x16 st[2];
        __builtin_amdgcn_s_setprio(1);
        #pragma unroll
        for (int ks = 0; ks < 2; ++ks) {
            f32x16 acc;
            #pragma unroll
            for (int r = 0; r < 16; ++r) acc[r] = 0.0f;
            #pragma unroll
            for (int dc = 0; dc < 5; ++dc)
                acc = __builtin_amdgcn_mfma_f32_32x32x16_bf16(kf[ks][dc], qf[dc], acc, 0, 0, 0);
            st[ks] = acc;
        }
        __builtin_amdgcn_s_setprio(0);

        // prefetch next K tile
        if (ti < 7) {
            #pragma unroll
            for (int ks = 0; ks < 2; ++ks)
                #pragma unroll
                for (int dc = 0; dc < 5; ++dc)
                    kf[ks][dc] = *(const bf16x8*)(kptr + (size_t)(ks * 5 + dc) * 512);
            kptr += 5120;
        }

        // P = exp2(st): partial accumulators break the serial sum chain
        unsigned int u[2][8];
        #pragma unroll
        for (int ks = 0; ks < 2; ++ks)
            #pragma unroll
            for (int jj = 0; jj < 8; ++jj) {
                const float p0 = exp2f(st[ks][2 * jj]);
                const float p1 = exp2f(st[ks][2 * jj + 1]);
                lp[jj & 3] += p0 + p1;
                asm("v_cvt_pk_bf16_f32 %0, %1, %2" : "=v"(u[ks][jj]) : "v"(p0), "v"(p1));
            }

        // P redistribution via permlane32_swap -> B-frag words
        uint4 F[2][2];
        #pragma unroll
        for (int ks = 0; ks < 2; ++ks) {
            unsigned a0 = u[ks][0], b0 = u[ks][2];
            unsigned a1 = u[ks][1], b1 = u[ks][3];
            asm("v_permlane32_swap_b32 %0, %1" : "+v"(a0), "+v"(b0));
            asm("v_permlane32_swap_b32 %0, %1" : "+v"(a1), "+v"(b1));
            F[ks][0] = make_uint4(a0, a1, b0, b1);
            unsigned a2 = u[ks][4], b2 = u[ks][6];
            unsigned a3 = u[ks][5], b3 = u[ks][7];
            asm("v_permlane32_swap_b32 %0, %1" : "+v"(a2), "+v"(b2));
            asm("v_permlane32_swap_b32 %0, %1" : "+v"(a3), "+v"(b3));
            F[ks][1] = make_uint4(a2, a3, b2, b3);
        }

        // PV
        __builtin_amdgcn_s_setprio(1);
        #pragma unroll
        for (int t = 0; t < 2; ++t)
            #pragma unroll
            for (int ks = 0; ks < 2; ++ks)
                #pragma unroll
                for (int kc = 0; kc < 2; ++kc)
                    OT[t] = __builtin_amdgcn_mfma_f32_32x32x16_bf16(
                        vf[t][ks][kc], __builtin_bit_cast(bf16x8, F[ks][kc]), OT[t], 0, 0, 0);
        __builtin_amdgcn_s_setprio(0);
    }

    const float lrun = (lp[0] + lp[1]) + (lp[2] + lp[3]);

    // ---- merge the two K-halves: pure sums (static softmax reference) ----
    if (khalf) {
        #pragma unroll
        for (int t = 0; t < 2; ++t)
            #pragma unroll
            for (int c = 0; c < 4; ++c)
                Osh[qhalf][t * 4 + c][l] = (f32x4){OT[t][4 * c], OT[t][4 * c + 1],
                                                   OT[t][4 * c + 2], OT[t][4 * c + 3]};
        lsh[qhalf][l] = lrun;
    }
    __syncthreads();
    if (khalf) return;

    #pragma unroll
    for (int t = 0; t < 2; ++t)
        #pragma unroll
        for (int c = 0; c < 4; ++c) {
            const f32x4 o = Osh[qhalf][t * 4 + c][l];
            OT[t][4 * c]     += o[0];
            OT[t][4 * c + 1] += o[1];
            OT[t][4 * c + 2] += o[2];
            OT[t][4 * c + 3] += o[3];
        }
    float lr = lrun + lsh[qhalf][l];
    lr += __shfl_xor(lr, 32);
    const float linv = 1.0f / lr;

    __bf16* oh = attn_h + (size_t)(b * S + q0 + lq) * DIMM + gh * HD;
    #pragma unroll
    for (int t = 0; t < 2; ++t)
        #pragma unroll
        for (int j = 0; j < 4; ++j) {
            const int d0 = 32 * t + 8 * j + 4 * h;
            unsigned short hv[4];
            #pragma unroll
            for (int c = 0; c < 4; ++c)
                hv[c] = __builtin_bit_cast(unsigned short, (__bf16)(OT[t][4 * j + c] * linv));
            *(ushort4*)(oh + d0) = make_ushort4(hv[0], hv[1], hv[2], hv[3]);
        }
}

extern "C" void kernel_launch(void* const* d_in, const int* in_sizes, int n_in,
                              void* d_out, int out_size, void* d_ws, size_t ws_size,
                              hipStream_t stream) {
    const float* x     = (const float*)d_in[0];
    const float* kv    = (const float*)d_in[1];
    const float* q_w   = (const float*)d_in[2];
    const float* q_b   = (const float*)d_in[3];
    const float* k_w   = (const float*)d_in[4];
    const float* k_b   = (const float*)d_in[5];
    const float* v_w   = (const float*)d_in[6];
    const float* v_b   = (const float*)d_in[7];
    const float* o_w   = (const float*)d_in[8];
    const float* o_b   = (const float*)d_in[9];
    const float* qn_g  = (const float*)d_in[10];
    const float* qn_b  = (const float*)d_in[11];
    const float* kn_g  = (const float*)d_in[12];
    const float* kn_b  = (const float*)d_in[13];
    const float* vemb  = (const float*)d_in[14];
    const int*   qvar  = (const int*)d_in[15];
    const int*   kvar  = (const int*)d_in[16];
    const int*   qtime = (const int*)d_in[17];
    const int*   ktime = (const int*)d_in[18];
    float* out = (float*)d_out;
    char*  W   = (char*)d_ws;

    const size_t MB = 1u << 20;
    __bf16* xh     = (__bf16*)(W);                   // 0-8   -> attn_h
    __bf16* kvh    = (__bf16*)(W + 8 * MB);          // 8-16  -> q_nb
    __bf16* q_nb   = (__bf16*)(W + 8 * MB);          // 8-18  (80-dim rows)
    __bf16* q_lin  = (__bf16*)(W + 18 * MB);         // 18-26
    __bf16* kv_lin = (__bf16*)(W + 26 * MB);         // 26-30
    __bf16* qwh    = (__bf16*)(W + 30 * MB);         // 30-32
    __bf16* kvwh   = (__bf16*)(W + 32 * MB);         // 32-33
    __bf16* kfrag  = (__bf16*)(W + 33 * MB);         // 33-35.5
    __bf16* vfrag  = (__bf16*)(W + 35 * MB + MB / 2);// 35.5-37.5
    __bf16* owh    = (__bf16*)(W + 37 * MB + MB / 2);// 37.5-39.5
    __bf16* owl    = (__bf16*)(W + 39 * MB + MB / 2);// 39.5-41.5
    float*  kvb    = (float*)(W + 42 * MB);          // 2 KB
    float2* rope   = (float2*)(W + 42 * MB + 4096);  // 128 KB
    __bf16* attn_h = xh;

    dim3 blk(256);

    cvt_all<<<5441, blk, 0, stream>>>(x, kv, q_w, k_w, v_w, o_w, k_b, v_b,
                                      xh, kvh, qwh, kvwh, owh, owl, kvb, rope);

    gemm_qkv<<<768, blk, 0, stream>>>(xh, qwh, q_b, q_lin, kvh, kvwh, kvb, kv_lin);

    transforms_all<<<20736, blk, 0, stream>>>(q_lin, kv_lin, qn_g, qn_b, kn_g, kn_b,
                                              qtime, ktime, qvar, kvar, vemb, rope,
                                              q_nb, kfrag, vfrag);

    flash_mfma<<<1024, blk, 0, stream>>>(q_nb, kfrag, vfrag, attn_h);

    gemm_o<<<dim3(16, 32), blk, 0, stream>>>(attn_h, owh, owl, o_b, out);
}